// Round 4
// baseline (73.768 us; speedup 1.0000x reference)
//
#include <hip/hip_runtime.h>

typedef __bf16 bf16x8 __attribute__((ext_vector_type(8)));
typedef float f32x4 __attribute__((ext_vector_type(4)));

__device__ __forceinline__ unsigned short f2b(float f) {
  union { float f; unsigned int u; } v;
  v.f = f;
  unsigned int r = v.u + 0x7fffu + ((v.u >> 16) & 1u);
  return (unsigned short)(r >> 16);
}
__device__ __forceinline__ float b2f_lo(unsigned int u) {
  union { unsigned int u; float f; } v;
  v.u = u << 16;
  return v.f;
}
__device__ __forceinline__ float b2f_hi(unsigned int u) {
  union { unsigned int u; float f; } v;
  v.u = u & 0xffff0000u;
  return v.f;
}

// ---------------- kernel 0: weight f32 [O][C][9] -> bf16 k-major [O][k*256+c] --
__global__ __launch_bounds__(256) void cast_weight(
    const float* __restrict__ w, unsigned short* __restrict__ wb) {
  int idx = blockIdx.x * 256 + threadIdx.x;  // 589824
  int o = idx / 2304;
  int r = idx - o * 2304;
  int k = r >> 8;
  int c = r & 255;
  wb[idx] = f2b(w[(size_t)(o * 256 + c) * 9 + k]);
}

// ---------------- kernel 1: x NCHW f32 -> NHWC bf16  x_t[b][h][w][c] ----------
__global__ __launch_bounds__(256) void transpose_x(
    const float* __restrict__ x, unsigned short* __restrict__ xt) {
  const int b = blockIdx.x >> 6;
  const int h = blockIdx.x & 63;
  const int t = threadIdx.x;
  const int wave = t >> 6, lane = t & 63;
  __shared__ float lds[64][65];
  const int wpos = t >> 2, sub = t & 3;
  const int cl0 = wave * 4 + (lane >> 4);
  const int w0 = (lane & 15) * 4;
  for (int cq = 0; cq < 4; ++cq) {
#pragma unroll
    for (int iter = 0; iter < 4; ++iter) {
      const int cl = iter * 16 + cl0;
      const int c = cq * 64 + cl;
      float4 v = *(const float4*)(x + (((size_t)b * 256 + c) * 64 + h) * 64 + w0);
      lds[cl][w0] = v.x; lds[cl][w0 + 1] = v.y;
      lds[cl][w0 + 2] = v.z; lds[cl][w0 + 3] = v.w;
    }
    __syncthreads();
    unsigned short hb[16];
#pragma unroll
    for (int j = 0; j < 16; ++j) hb[j] = f2b(lds[sub * 16 + j][wpos]);
    uint4 p0, p1;
    p0.x = (unsigned)hb[0] | ((unsigned)hb[1] << 16);
    p0.y = (unsigned)hb[2] | ((unsigned)hb[3] << 16);
    p0.z = (unsigned)hb[4] | ((unsigned)hb[5] << 16);
    p0.w = (unsigned)hb[6] | ((unsigned)hb[7] << 16);
    p1.x = (unsigned)hb[8] | ((unsigned)hb[9] << 16);
    p1.y = (unsigned)hb[10] | ((unsigned)hb[11] << 16);
    p1.z = (unsigned)hb[12] | ((unsigned)hb[13] << 16);
    p1.w = (unsigned)hb[14] | ((unsigned)hb[15] << 16);
    unsigned short* dst = xt + (((size_t)b * 64 + h) * 64 + wpos) * 256 + cq * 64 + sub * 16;
    *(uint4*)dst = p0;
    *(uint4*)(dst + 8) = p1;
    __syncthreads();
  }
}

// ---------------- fused: sample + GEMM -------------------------------------
// block = (b, nt=h). Out tile [256 o][64 hw]. K = k*256+c, 72 steps of 32.
// 512 threads = 8 waves (4m x 2n). Bs built in-LDS from x_t; As via G2L.
// Counted-vmcnt 2-phase loop (T4) + 16B-column XOR swizzle (T2).
#define G2L(gsrc, ldst)                                                            \
  __builtin_amdgcn_global_load_lds(                                                \
      (const __attribute__((address_space(1))) void*)(gsrc),                       \
      (__attribute__((address_space(3))) void*)(ldst), 16, 0, 0)

__device__ __forceinline__ void load_taps(uint2 q[4], const unsigned short* t0,
                                          const unsigned short* t1,
                                          const unsigned short* t2,
                                          const unsigned short* t3, int eoff) {
  q[0] = *(const uint2*)(t0 + eoff);
  q[1] = *(const uint2*)(t1 + eoff);
  q[2] = *(const uint2*)(t2 + eoff);
  q[3] = *(const uint2*)(t3 + eoff);
}

__device__ __forceinline__ void combine_write(const uint2 q[4], float4 wt,
                                              __bf16* dst) {
  float v0 = wt.x * b2f_lo(q[0].x) + wt.y * b2f_lo(q[1].x) +
             wt.z * b2f_lo(q[2].x) + wt.w * b2f_lo(q[3].x);
  float v1 = wt.x * b2f_hi(q[0].x) + wt.y * b2f_hi(q[1].x) +
             wt.z * b2f_hi(q[2].x) + wt.w * b2f_hi(q[3].x);
  float v2 = wt.x * b2f_lo(q[0].y) + wt.y * b2f_lo(q[1].y) +
             wt.z * b2f_lo(q[2].y) + wt.w * b2f_lo(q[3].y);
  float v3 = wt.x * b2f_hi(q[0].y) + wt.y * b2f_hi(q[1].y) +
             wt.z * b2f_hi(q[2].y) + wt.w * b2f_hi(q[3].y);
  uint2 r;
  r.x = (unsigned)f2b(v0) | ((unsigned)f2b(v1) << 16);
  r.y = (unsigned)f2b(v2) | ((unsigned)f2b(v3) << 16);
  *(uint2*)dst = r;
}

__global__ __launch_bounds__(512) void dcn_fused(
    const unsigned short* __restrict__ xt, const float* __restrict__ off,
    const float* __restrict__ mask, const __bf16* __restrict__ wbf,
    const float* __restrict__ bias, float* __restrict__ out) {
  const int bid = blockIdx.x;
  const int id = ((bid & 7) << 5) | (bid >> 3);  // XCD-contiguous, bijective (256=8*32)
  const int b = id >> 6;
  const int nt = id & 63;  // = h row

  const int tid = threadIdx.x;
  const int lane = tid & 63;
  const int wave = tid >> 6;
  const int wm = wave >> 1, wn = wave & 1;
  const int lh = lane & 15, lg = lane >> 4;

  __shared__ __align__(16) __bf16 As[2][256 * 32];  // 32 KB
  __shared__ __align__(16) __bf16 Bs[2][64 * 32];   // 8 KB
  __shared__ __align__(16) float swt[9][64][4];     // 9 KB
  __shared__ __align__(16) int sidx[9][64][4];      // 9 KB

  // ---- precompute per-(pos,k) tap weights & indices ----
  for (int pair = tid; pair < 576; pair += 512) {
    const int k = pair >> 6;   // 0..8
    const int pl = pair & 63;  // = w
    float oy = off[(((size_t)b * 18 + 2 * k) * 64 + nt) * 64 + pl];
    float ox = off[(((size_t)b * 18 + 2 * k + 1) * 64 + nt) * 64 + pl];
    float m = mask[(((size_t)b * 9 + k) * 64 + nt) * 64 + pl];
    float py = oy + (float)(nt - 1 + k / 3);
    float px = ox + (float)(pl - 1 + k % 3);
    float y0f = floorf(py), x0f = floorf(px);
    float ly = py - y0f, lx = px - x0f;
    float hy = 1.f - ly, hx = 1.f - lx;
    int y0 = (int)y0f, x0 = (int)x0f;
    int y1 = y0 + 1, x1 = x0 + 1;
    bool vy0 = (y0 >= 0) && (y0 < 64);
    bool vy1 = (y1 >= 0) && (y1 < 64);
    bool vx0 = (x0 >= 0) && (x0 < 64);
    bool vx1 = (x1 >= 0) && (x1 < 64);
    int yc0 = min(max(y0, 0), 63), yc1 = min(max(y1, 0), 63);
    int xc0 = min(max(x0, 0), 63), xc1 = min(max(x1, 0), 63);
    sidx[k][pl][0] = (yc0 * 64 + xc0) * 256;
    sidx[k][pl][1] = (yc0 * 64 + xc1) * 256;
    sidx[k][pl][2] = (yc1 * 64 + xc0) * 256;
    sidx[k][pl][3] = (yc1 * 64 + xc1) * 256;
    swt[k][pl][0] = (vy0 && vx0) ? hy * hx * m : 0.f;
    swt[k][pl][1] = (vy0 && vx1) ? hy * lx * m : 0.f;
    swt[k][pl][2] = (vy1 && vx0) ? ly * hx * m : 0.f;
    swt[k][pl][3] = (vy1 && vx1) ? ly * lx * m : 0.f;
  }

  // ---- staging geometry ----
  // A: thread tid fills LDS chunk tid (linear); global src column pre-swizzled:
  // LDS (row, c) holds global kcol = c ^ ((row>>1)&3).
  const int rowA0 = tid >> 2;
  const int koS = (((tid & 3) ^ ((tid >> 3) & 3)) * 8);
  const __bf16* aP0 = wbf + (size_t)rowA0 * 2304 + koS;
  const __bf16* aP1 = wbf + (size_t)(rowA0 + 128) * 2304 + koS;

  const int pos = tid >> 3, ci = tid & 7;
  const unsigned short* xtb = xt + (size_t)b * 1048576 + ci * 4;
  // Bs write: row=pos, 16B-col (ci>>1) ^ ((pos>>1)&3), 8B half (ci&1)
  const int bsw = pos * 32 + ((((ci >> 1) ^ ((pos >> 1) & 3)) << 3) | ((ci & 1) << 2));

  // MFMA fragment read offsets (elements), same swizzle: c = lg ^ ((lh>>1)&3)
  const int cA = lg ^ ((lh >> 1) & 3);
  const int aoff = (wm * 64 + lh) * 32 + cA * 8;
  const int boff = (wn * 32 + lh) * 32 + cA * 8;

#define MFMA_STEP(P)                                                               \
  do {                                                                             \
    const __bf16* app = &As[P][aoff];                                              \
    const __bf16* bpp = &Bs[P][boff];                                              \
    bf16x8 af[4], bf2[2];                                                          \
    _Pragma("unroll") for (int fm = 0; fm < 4; ++fm)                               \
        af[fm] = *(const bf16x8*)(app + fm * 16 * 32);                             \
    _Pragma("unroll") for (int fn = 0; fn < 2; ++fn)                               \
        bf2[fn] = *(const bf16x8*)(bpp + fn * 16 * 32);                            \
    _Pragma("unroll") for (int fm = 0; fm < 4; ++fm)                               \
        _Pragma("unroll") for (int fn = 0; fn < 2; ++fn)                           \
            acc[fm][fn] = __builtin_amdgcn_mfma_f32_16x16x32_bf16(                 \
                af[fm], bf2[fn], acc[fm][fn], 0, 0, 0);                            \
  } while (0)

#define WAIT_BAR(N)                                                                \
  do {                                                                             \
    asm volatile("s_waitcnt vmcnt(" #N ") lgkmcnt(0)" ::: "memory");               \
    __builtin_amdgcn_sched_barrier(0);                                             \
    __builtin_amdgcn_s_barrier();                                                  \
  } while (0)

  f32x4 acc[4][2] = {};
  uint2 q0[4], q1[4];
  float4 wt4;
  const unsigned short *t0, *t1, *t2, *t3;

  __syncthreads();  // swt/sidx ready

  // ---- prologue ----
  wt4 = *(const float4*)&swt[0][pos][0];
  {
    int4 ix = *(const int4*)&sidx[0][pos][0];
    t0 = xtb + ix.x; t1 = xtb + ix.y; t2 = xtb + ix.z; t3 = xtb + ix.w;
  }
  load_taps(q0, t0, t1, t2, t3, 0);
  combine_write(q0, wt4, &Bs[0][bsw]);   // step 0 (compiler drains q0 here)
  G2L(aP0, &As[0][tid * 8]);
  G2L(aP1, &As[0][(tid + 512) * 8]);
  __builtin_amdgcn_sched_barrier(0);     // pin: G2L before taps in vmcnt order
  load_taps(q1, t0, t1, t2, t3, 32);     // taps for step 1
  WAIT_BAR(4);                           // G2L(0) done; q1 in flight

  for (int kt = 0; kt < 70; kt += 2) {
    // ---- even body: MFMA step kt (bufs 0), build step kt+1 (bufs 1) ----
    G2L(aP0 + (kt + 1) * 32, &As[1][tid * 8]);
    G2L(aP1 + (kt + 1) * 32, &As[1][(tid + 512) * 8]);
    __builtin_amdgcn_sched_barrier(0);
    if ((kt & 7) == 6) {  // tap pointers for k'' = (kt+2)>>3
      int4 ix = *(const int4*)&sidx[(kt + 2) >> 3][pos][0];
      t0 = xtb + ix.x; t1 = xtb + ix.y; t2 = xtb + ix.z; t3 = xtb + ix.w;
    }
    load_taps(q0, t0, t1, t2, t3, ((kt + 2) & 7) * 32);  // taps for step kt+2
    combine_write(q1, wt4, &Bs[1][bsw]);                 // step kt+1
    MFMA_STEP(0);
    WAIT_BAR(4);  // A(kt+1) done; q0 in flight

    // ---- odd body: MFMA step kt+1 (bufs 1), build step kt+2 (bufs 0) ----
    G2L(aP0 + (kt + 2) * 32, &As[0][tid * 8]);
    G2L(aP1 + (kt + 2) * 32, &As[0][(tid + 512) * 8]);
    __builtin_amdgcn_sched_barrier(0);
    if ((kt & 7) == 6) wt4 = *(const float4*)&swt[(kt + 2) >> 3][pos][0];
    load_taps(q1, t0, t1, t2, t3, ((kt + 3) & 7) * 32);  // taps for step kt+3
    combine_write(q0, wt4, &Bs[0][bsw]);                 // step kt+2
    MFMA_STEP(1);
    WAIT_BAR(4);  // A(kt+2) done; q1 in flight
  }

  // ---- tail: steps 70, 71 ----
  G2L(aP0 + 71 * 32, &As[1][tid * 8]);
  G2L(aP1 + 71 * 32, &As[1][(tid + 512) * 8]);
  combine_write(q1, wt4, &Bs[1][bsw]);   // step 71 (q1 = taps(71), k=8)
  MFMA_STEP(0);                          // step 70
  WAIT_BAR(0);
  MFMA_STEP(1);                          // step 71

  // ---- epilogue ----
  float* outb = out + (size_t)b * 256 * 4096 + (size_t)nt * 64;
#pragma unroll
  for (int fm = 0; fm < 4; ++fm) {
#pragma unroll
    for (int i = 0; i < 4; ++i) {
      const int o = wm * 64 + fm * 16 + lg * 4 + i;
      const float bs = bias[o];
      float* orow = outb + (size_t)o * 4096 + wn * 32 + lh;
#pragma unroll
      for (int fn = 0; fn < 2; ++fn) orow[fn * 16] = acc[fm][fn][i] + bs;
    }
  }
#undef MFMA_STEP
#undef WAIT_BAR
}

extern "C" void kernel_launch(void* const* d_in, const int* in_sizes, int n_in,
                              void* d_out, int out_size, void* d_ws, size_t ws_size,
                              hipStream_t stream) {
  const float* x = (const float*)d_in[0];
  const float* off = (const float*)d_in[1];
  const float* mask = (const float*)d_in[2];
  const float* wgt = (const float*)d_in[3];
  const float* bias = (const float*)d_in[4];
  float* out = (float*)d_out;

  unsigned short* wbf = (unsigned short*)d_ws;   // 256*2304 bf16 = 1.2 MB
  unsigned short* xt = wbf + 589824ull;          // 4*64*64*256 bf16 = 8.4 MB

  cast_weight<<<2304, 256, 0, stream>>>(wgt, wbf);
  transpose_x<<<256, 256, 0, stream>>>(x, xt);
  dcn_fused<<<256, 512, 0, stream>>>(xt, off, mask, (const __bf16*)wbf, bias, out);
}

// Round 5
// 69.541 us; speedup vs baseline: 1.0608x; 1.0608x over previous
//
#include <hip/hip_runtime.h>

typedef __bf16 bf16x8 __attribute__((ext_vector_type(8)));
typedef float f32x4 __attribute__((ext_vector_type(4)));

__device__ __forceinline__ unsigned short f2b(float f) {
  union { float f; unsigned int u; } v;
  v.f = f;
  unsigned int r = v.u + 0x7fffu + ((v.u >> 16) & 1u);
  return (unsigned short)(r >> 16);
}
__device__ __forceinline__ float b2f_lo(unsigned int u) {
  union { unsigned int u; float f; } v;
  v.u = u << 16;
  return v.f;
}
__device__ __forceinline__ float b2f_hi(unsigned int u) {
  union { unsigned int u; float f; } v;
  v.u = u & 0xffff0000u;
  return v.f;
}

// ---------------- kernel 0: weight f32 [O][C][9] -> bf16 k-major [O][k*256+c] --
__global__ __launch_bounds__(256) void cast_weight(
    const float* __restrict__ w, unsigned short* __restrict__ wb) {
  int idx = blockIdx.x * 256 + threadIdx.x;  // 589824
  int o = idx / 2304;
  int r = idx - o * 2304;
  int k = r >> 8;
  int c = r & 255;
  wb[idx] = f2b(w[(size_t)(o * 256 + c) * 9 + k]);
}

// ---------------- kernel 1: x NCHW f32 -> NHWC bf16  x_t[b][h][w][c] ----------
__global__ __launch_bounds__(256) void transpose_x(
    const float* __restrict__ x, unsigned short* __restrict__ xt) {
  const int b = blockIdx.x >> 6;
  const int h = blockIdx.x & 63;
  const int t = threadIdx.x;
  const int wave = t >> 6, lane = t & 63;
  __shared__ float lds[64][65];
  const int wpos = t >> 2, sub = t & 3;
  const int cl0 = wave * 4 + (lane >> 4);
  const int w0 = (lane & 15) * 4;
  for (int cq = 0; cq < 4; ++cq) {
#pragma unroll
    for (int iter = 0; iter < 4; ++iter) {
      const int cl = iter * 16 + cl0;
      const int c = cq * 64 + cl;
      float4 v = *(const float4*)(x + (((size_t)b * 256 + c) * 64 + h) * 64 + w0);
      lds[cl][w0] = v.x; lds[cl][w0 + 1] = v.y;
      lds[cl][w0 + 2] = v.z; lds[cl][w0 + 3] = v.w;
    }
    __syncthreads();
    unsigned short hb[16];
#pragma unroll
    for (int j = 0; j < 16; ++j) hb[j] = f2b(lds[sub * 16 + j][wpos]);
    uint4 p0, p1;
    p0.x = (unsigned)hb[0] | ((unsigned)hb[1] << 16);
    p0.y = (unsigned)hb[2] | ((unsigned)hb[3] << 16);
    p0.z = (unsigned)hb[4] | ((unsigned)hb[5] << 16);
    p0.w = (unsigned)hb[6] | ((unsigned)hb[7] << 16);
    p1.x = (unsigned)hb[8] | ((unsigned)hb[9] << 16);
    p1.y = (unsigned)hb[10] | ((unsigned)hb[11] << 16);
    p1.z = (unsigned)hb[12] | ((unsigned)hb[13] << 16);
    p1.w = (unsigned)hb[14] | ((unsigned)hb[15] << 16);
    unsigned short* dst = xt + (((size_t)b * 64 + h) * 64 + wpos) * 256 + cq * 64 + sub * 16;
    *(uint4*)dst = p0;
    *(uint4*)(dst + 8) = p1;
    __syncthreads();
  }
}

// ---------------- fused: sample + GEMM, BK=64 phases (T3+T4) ----------------
// block = (b, nt=h). Out tile [256 o][64 hw]. 36 phases of K=64 (tap k = kt>>2,
// channel base (kt&3)*64). 512 threads = 8 waves (4m x 2n). Dynamic LDS 98KB:
// As[2][2][256*32], Bs[2][2][64*32] (32-wide subtiles keep the verified
// 0-conflict XOR swizzle), swt/sidx [9][64][4].
#define G2L(gsrc, ldst)                                                            \
  __builtin_amdgcn_global_load_lds(                                                \
      (const __attribute__((address_space(1))) void*)(gsrc),                       \
      (__attribute__((address_space(3))) void*)(ldst), 16, 0, 0)

__device__ __forceinline__ void combine8(uint4 q0, uint4 q1, uint4 q2, uint4 q3,
                                         float4 wt, __bf16* dst) {
  float v0 = wt.x * b2f_lo(q0.x), v1 = wt.x * b2f_hi(q0.x);
  float v2 = wt.x * b2f_lo(q0.y), v3 = wt.x * b2f_hi(q0.y);
  float v4 = wt.x * b2f_lo(q0.z), v5 = wt.x * b2f_hi(q0.z);
  float v6 = wt.x * b2f_lo(q0.w), v7 = wt.x * b2f_hi(q0.w);
  v0 += wt.y * b2f_lo(q1.x); v1 += wt.y * b2f_hi(q1.x);
  v2 += wt.y * b2f_lo(q1.y); v3 += wt.y * b2f_hi(q1.y);
  v4 += wt.y * b2f_lo(q1.z); v5 += wt.y * b2f_hi(q1.z);
  v6 += wt.y * b2f_lo(q1.w); v7 += wt.y * b2f_hi(q1.w);
  v0 += wt.z * b2f_lo(q2.x); v1 += wt.z * b2f_hi(q2.x);
  v2 += wt.z * b2f_lo(q2.y); v3 += wt.z * b2f_hi(q2.y);
  v4 += wt.z * b2f_lo(q2.z); v5 += wt.z * b2f_hi(q2.z);
  v6 += wt.z * b2f_lo(q2.w); v7 += wt.z * b2f_hi(q2.w);
  v0 += wt.w * b2f_lo(q3.x); v1 += wt.w * b2f_hi(q3.x);
  v2 += wt.w * b2f_lo(q3.y); v3 += wt.w * b2f_hi(q3.y);
  v4 += wt.w * b2f_lo(q3.z); v5 += wt.w * b2f_hi(q3.z);
  v6 += wt.w * b2f_lo(q3.w); v7 += wt.w * b2f_hi(q3.w);
  uint4 r;
  r.x = (unsigned)f2b(v0) | ((unsigned)f2b(v1) << 16);
  r.y = (unsigned)f2b(v2) | ((unsigned)f2b(v3) << 16);
  r.z = (unsigned)f2b(v4) | ((unsigned)f2b(v5) << 16);
  r.w = (unsigned)f2b(v6) | ((unsigned)f2b(v7) << 16);
  *(uint4*)dst = r;
}

__global__ __launch_bounds__(512) void dcn_fused(
    const unsigned short* __restrict__ xt, const float* __restrict__ off,
    const float* __restrict__ mask, const __bf16* __restrict__ wbf,
    const float* __restrict__ bias, float* __restrict__ out) {
  extern __shared__ char smem_raw[];
  __bf16* As = (__bf16*)smem_raw;           // 2 bufs x 16384 el = 65536 B
  __bf16* Bs = As + 32768;                  // 2 bufs x 4096 el  = 16384 B
  float* swt = (float*)(Bs + 8192);         // [9][64][4] = 9216 B
  int* sidx = (int*)(swt + 2304);           // [9][64][4] = 9216 B

  const int bid = blockIdx.x;
  const int id = ((bid & 7) << 5) | (bid >> 3);  // XCD-contiguous, bijective
  const int b = id >> 6;
  const int nt = id & 63;  // = h row

  const int tid = threadIdx.x;
  const int lane = tid & 63;
  const int wave = tid >> 6;
  const int wm = wave >> 1, wn = wave & 1;
  const int lh = lane & 15, lg = lane >> 4;

  // ---- precompute per-(pos,k) tap weights & indices ----
  for (int pair = tid; pair < 576; pair += 512) {
    const int k = pair >> 6;   // 0..8
    const int pl = pair & 63;  // = w
    float oy = off[(((size_t)b * 18 + 2 * k) * 64 + nt) * 64 + pl];
    float ox = off[(((size_t)b * 18 + 2 * k + 1) * 64 + nt) * 64 + pl];
    float m = mask[(((size_t)b * 9 + k) * 64 + nt) * 64 + pl];
    float py = oy + (float)(nt - 1 + k / 3);
    float px = ox + (float)(pl - 1 + k % 3);
    float y0f = floorf(py), x0f = floorf(px);
    float ly = py - y0f, lx = px - x0f;
    float hy = 1.f - ly, hx = 1.f - lx;
    int y0 = (int)y0f, x0 = (int)x0f;
    int y1 = y0 + 1, x1 = x0 + 1;
    bool vy0 = (y0 >= 0) && (y0 < 64);
    bool vy1 = (y1 >= 0) && (y1 < 64);
    bool vx0 = (x0 >= 0) && (x0 < 64);
    bool vx1 = (x1 >= 0) && (x1 < 64);
    int yc0 = min(max(y0, 0), 63), yc1 = min(max(y1, 0), 63);
    int xc0 = min(max(x0, 0), 63), xc1 = min(max(x1, 0), 63);
    int* sp = sidx + (k * 64 + pl) * 4;
    float* wp = swt + (k * 64 + pl) * 4;
    sp[0] = (yc0 * 64 + xc0) * 256;
    sp[1] = (yc0 * 64 + xc1) * 256;
    sp[2] = (yc1 * 64 + xc0) * 256;
    sp[3] = (yc1 * 64 + xc1) * 256;
    wp[0] = (vy0 && vx0) ? hy * hx * m : 0.f;
    wp[1] = (vy0 && vx1) ? hy * lx * m : 0.f;
    wp[2] = (vy1 && vx0) ? ly * hx * m : 0.f;
    wp[3] = (vy1 && vx1) ? ly * lx * m : 0.f;
  }

  // ---- A staging geometry (4 G2L per phase, 32-wide subtile swizzle) ----
  // j: L=j*512+tid; ks=L>>10; r=L&1023; row=r>>2; ch4=r&3; swz=ch4^((row>>1)&3)
  const __bf16* aSrc[4];
  int aDst[4];
#pragma unroll
  for (int j = 0; j < 4; ++j) {
    const int L = j * 512 + tid;
    const int ksj = L >> 10;
    const int r = L & 1023;
    const int row = r >> 2;
    const int swz = (r & 3) ^ ((row >> 1) & 3);
    aSrc[j] = wbf + (size_t)row * 2304 + ksj * 32 + swz * 8;
    aDst[j] = L * 8;  // element offset within an As buffer
  }

  // ---- B build geometry ----
  const int pos = tid >> 3, ci = tid & 7;
  const unsigned short* xtb = xt + (size_t)b * 1048576 + ci * 8;
  const int bsw = (ci >> 2) * 2048 + pos * 32 + (((ci & 3) ^ ((pos >> 1) & 3)) * 8);

  // ---- MFMA fragment offsets ----
  const int csw = (lg ^ ((lh >> 1) & 3)) * 8;
  int aoff[4], boff[2];
#pragma unroll
  for (int fm = 0; fm < 4; ++fm) aoff[fm] = (wm * 64 + fm * 16 + lh) * 32 + csw;
#pragma unroll
  for (int fn = 0; fn < 2; ++fn) boff[fn] = (wn * 32 + fn * 16 + lh) * 32 + csw;

#define MFMA_PHASE(BUF)                                                            \
  do {                                                                             \
    const __bf16* Ab = As + (BUF) * 16384;                                         \
    const __bf16* Bb = Bs + (BUF) * 4096;                                          \
    bf16x8 a0[4], a1[4], b0[2], b1[2];                                             \
    _Pragma("unroll") for (int fm = 0; fm < 4; ++fm) {                             \
      a0[fm] = *(const bf16x8*)(Ab + aoff[fm]);                                    \
      a1[fm] = *(const bf16x8*)(Ab + 8192 + aoff[fm]);                             \
    }                                                                              \
    _Pragma("unroll") for (int fn = 0; fn < 2; ++fn) {                             \
      b0[fn] = *(const bf16x8*)(Bb + boff[fn]);                                    \
      b1[fn] = *(const bf16x8*)(Bb + 2048 + boff[fn]);                             \
    }                                                                              \
    _Pragma("unroll") for (int fm = 0; fm < 4; ++fm)                               \
        _Pragma("unroll") for (int fn = 0; fn < 2; ++fn) {                         \
      acc[fm][fn] = __builtin_amdgcn_mfma_f32_16x16x32_bf16(a0[fm], b0[fn],        \
                                                            acc[fm][fn], 0, 0, 0); \
      acc[fm][fn] = __builtin_amdgcn_mfma_f32_16x16x32_bf16(a1[fm], b1[fn],        \
                                                            acc[fm][fn], 0, 0, 0); \
    }                                                                              \
  } while (0)

#define WAIT_BAR(N)                                                                \
  do {                                                                             \
    asm volatile("s_waitcnt vmcnt(" #N ") lgkmcnt(0)" ::: "memory");               \
    __builtin_amdgcn_sched_barrier(0);                                             \
    __builtin_amdgcn_s_barrier();                                                  \
  } while (0)

#define STAGE_A(KT, BUF)                                                           \
  do {                                                                             \
    __bf16* AsD = As + (BUF) * 16384;                                              \
    G2L(aSrc[0] + (KT) * 64, AsD + aDst[0]);                                       \
    G2L(aSrc[1] + (KT) * 64, AsD + aDst[1]);                                       \
    G2L(aSrc[2] + (KT) * 64, AsD + aDst[2]);                                       \
    G2L(aSrc[3] + (KT) * 64, AsD + aDst[3]);                                       \
  } while (0)

#define LOADTAPS(Q0, Q1, Q2, Q3, IX, CO)                                           \
  do {                                                                             \
    Q0 = *(const uint4*)(xtb + (IX).x + (CO));                                     \
    Q1 = *(const uint4*)(xtb + (IX).y + (CO));                                     \
    Q2 = *(const uint4*)(xtb + (IX).z + (CO));                                     \
    Q3 = *(const uint4*)(xtb + (IX).w + (CO));                                     \
  } while (0)

  // phase p: G2L(tile p+1 -> As[(p+1)&1]); taps(tile p+2) -> qLoad;
  // combine(qComb = tile p+1, wt[(p+1)>>2]) -> Bs[(p+1)&1]; MFMA(tile p, buf p&1)
#define PHASE(P_, QL0, QL1, QL2, QL3, QC0, QC1, QC2, QC3)                          \
  do {                                                                             \
    const int kt1 = (P_) + 1, kt2 = (P_) + 2;                                      \
    const int BC = kt1 & 1;                                                        \
    STAGE_A(kt1, BC);                                                              \
    __builtin_amdgcn_sched_barrier(0);                                             \
    float4 wt4 = *(const float4*)(swt + ((kt1 >> 2) * 64 + pos) * 4);              \
    int4 ix = *(const int4*)(sidx + ((kt2 >> 2) * 64 + pos) * 4);                  \
    LOADTAPS(QL0, QL1, QL2, QL3, ix, (kt2 & 3) * 64);                              \
    combine8(QC0, QC1, QC2, QC3, wt4, Bs + BC * 4096 + bsw);                       \
    __builtin_amdgcn_s_setprio(1);                                                 \
    MFMA_PHASE((P_) & 1);                                                          \
    __builtin_amdgcn_s_setprio(0);                                                 \
    WAIT_BAR(4);                                                                   \
  } while (0)

  f32x4 acc[4][2] = {};
  uint4 qA0, qA1, qA2, qA3, qB0, qB1, qB2, qB3;

  __syncthreads();  // swt/sidx ready

  // ---- prologue: tile0 build + tile0 A-stage + tile1 taps ----
  {
    float4 wt0 = *(const float4*)(swt + pos * 4);
    int4 ix0 = *(const int4*)(sidx + pos * 4);
    LOADTAPS(qA0, qA1, qA2, qA3, ix0, 0);
    combine8(qA0, qA1, qA2, qA3, wt0, Bs + bsw);
    STAGE_A(0, 0);
    __builtin_amdgcn_sched_barrier(0);
    LOADTAPS(qB0, qB1, qB2, qB3, ix0, 64);
    WAIT_BAR(4);
  }

  for (int p = 0; p < 34; p += 2) {
    PHASE(p, qA0, qA1, qA2, qA3, qB0, qB1, qB2, qB3);
    PHASE(p + 1, qB0, qB1, qB2, qB3, qA0, qA1, qA2, qA3);
  }
  // ---- tail: phase 34 (no tap prefetch), phase 35 (MFMA only) ----
  {
    STAGE_A(35, 1);
    float4 wt4 = *(const float4*)(swt + (8 * 64 + pos) * 4);
    combine8(qB0, qB1, qB2, qB3, wt4, Bs + 4096 + bsw);
    __builtin_amdgcn_s_setprio(1);
    MFMA_PHASE(0);
    __builtin_amdgcn_s_setprio(0);
    WAIT_BAR(0);
    MFMA_PHASE(1);
  }

  // ---- epilogue ----
  float* outb = out + (size_t)b * 256 * 4096 + (size_t)nt * 64;
#pragma unroll
  for (int fm = 0; fm < 4; ++fm) {
#pragma unroll
    for (int i = 0; i < 4; ++i) {
      const int o = wm * 64 + fm * 16 + lg * 4 + i;
      const float bs = bias[o];
      float* orow = outb + (size_t)o * 4096 + wn * 32 + lh;
#pragma unroll
      for (int fn = 0; fn < 2; ++fn) orow[fn * 16] = acc[fm][fn][i] + bs;
    }
  }
#undef MFMA_PHASE
#undef WAIT_BAR
#undef STAGE_A
#undef LOADTAPS
#undef PHASE
}

extern "C" void kernel_launch(void* const* d_in, const int* in_sizes, int n_in,
                              void* d_out, int out_size, void* d_ws, size_t ws_size,
                              hipStream_t stream) {
  const float* x = (const float*)d_in[0];
  const float* off = (const float*)d_in[1];
  const float* mask = (const float*)d_in[2];
  const float* wgt = (const float*)d_in[3];
  const float* bias = (const float*)d_in[4];
  float* out = (float*)d_out;

  unsigned short* wbf = (unsigned short*)d_ws;   // 256*2304 bf16 = 1.2 MB
  unsigned short* xtp = wbf + 589824ull;         // 4*64*64*256 bf16 = 8.4 MB

  const int smem_bytes = 65536 + 16384 + 9216 + 9216;  // 100352
  (void)hipFuncSetAttribute(reinterpret_cast<const void*>(&dcn_fused),
                            hipFuncAttributeMaxDynamicSharedMemorySize, smem_bytes);

  cast_weight<<<2304, 256, 0, stream>>>(wgt, wbf);
  transpose_x<<<256, 256, 0, stream>>>(x, xtp);
  dcn_fused<<<256, 512, smem_bytes, stream>>>(xtp, off, mask, (const __bf16*)wbf,
                                              bias, out);
}

// Round 6
// 69.159 us; speedup vs baseline: 1.0667x; 1.0055x over previous
//
#include <hip/hip_runtime.h>

typedef __bf16 bf16x8 __attribute__((ext_vector_type(8)));
typedef float f32x4 __attribute__((ext_vector_type(4)));

__device__ __forceinline__ unsigned short f2b(float f) {
  union { float f; unsigned int u; } v;
  v.f = f;
  unsigned int r = v.u + 0x7fffu + ((v.u >> 16) & 1u);
  return (unsigned short)(r >> 16);
}
__device__ __forceinline__ float b2f_lo(unsigned int u) {
  union { unsigned int u; float f; } v;
  v.u = u << 16;
  return v.f;
}
__device__ __forceinline__ float b2f_hi(unsigned int u) {
  union { unsigned int u; float f; } v;
  v.u = u & 0xffff0000u;
  return v.f;
}

// ---------------- kernel 0: weight f32 [O][C][9] -> bf16 k-major [O][k*256+c] --
__global__ __launch_bounds__(256) void cast_weight(
    const float* __restrict__ w, unsigned short* __restrict__ wb) {
  int idx = blockIdx.x * 256 + threadIdx.x;  // 589824
  int o = idx / 2304;
  int r = idx - o * 2304;
  int k = r >> 8;
  int c = r & 255;
  wb[idx] = f2b(w[(size_t)(o * 256 + c) * 9 + k]);
}

// ---------------- kernel 1: x NCHW f32 -> NHWC bf16  x_t[b][h][w][c] ----------
// grid 1024 = (b, h, cq): 4 blocks/CU for latency hiding.
__global__ __launch_bounds__(256) void transpose_x(
    const float* __restrict__ x, unsigned short* __restrict__ xt) {
  const int bid = blockIdx.x;
  const int b = bid >> 8;
  const int h = (bid >> 2) & 63;
  const int cq = bid & 3;
  const int t = threadIdx.x;
  const int wave = t >> 6, lane = t & 63;
  __shared__ float lds[64][65];
  const int wpos = t >> 2, sub = t & 3;
  const int cl0 = wave * 4 + (lane >> 4);
  const int w0 = (lane & 15) * 4;
#pragma unroll
  for (int iter = 0; iter < 4; ++iter) {
    const int cl = iter * 16 + cl0;
    const int c = cq * 64 + cl;
    float4 v = *(const float4*)(x + (((size_t)b * 256 + c) * 64 + h) * 64 + w0);
    lds[cl][w0] = v.x; lds[cl][w0 + 1] = v.y;
    lds[cl][w0 + 2] = v.z; lds[cl][w0 + 3] = v.w;
  }
  __syncthreads();
  unsigned short hb[16];
#pragma unroll
  for (int j = 0; j < 16; ++j) hb[j] = f2b(lds[sub * 16 + j][wpos]);
  uint4 p0, p1;
  p0.x = (unsigned)hb[0] | ((unsigned)hb[1] << 16);
  p0.y = (unsigned)hb[2] | ((unsigned)hb[3] << 16);
  p0.z = (unsigned)hb[4] | ((unsigned)hb[5] << 16);
  p0.w = (unsigned)hb[6] | ((unsigned)hb[7] << 16);
  p1.x = (unsigned)hb[8] | ((unsigned)hb[9] << 16);
  p1.y = (unsigned)hb[10] | ((unsigned)hb[11] << 16);
  p1.z = (unsigned)hb[12] | ((unsigned)hb[13] << 16);
  p1.w = (unsigned)hb[14] | ((unsigned)hb[15] << 16);
  unsigned short* dst = xt + (((size_t)b * 64 + h) * 64 + wpos) * 256 + cq * 64 + sub * 16;
  *(uint4*)dst = p0;
  *(uint4*)(dst + 8) = p1;
}

// ---------------- fused: sample + GEMM, BK=64 phases, 2 blocks/CU ------------
// block = (b, nt=h, nh=half-row). Out tile [256 o][32 hw]. 36 phases of K=64.
// 256 threads = 4 waves (4m x 1n). LDS 78.75KB/block -> 2 blocks/CU overlap.
#define G2L(gsrc, ldst)                                                            \
  __builtin_amdgcn_global_load_lds(                                                \
      (const __attribute__((address_space(1))) void*)(gsrc),                       \
      (__attribute__((address_space(3))) void*)(ldst), 16, 0, 0)

__device__ __forceinline__ void combine8(uint4 q0, uint4 q1, uint4 q2, uint4 q3,
                                         float4 wt, __bf16* dst) {
  float v0 = wt.x * b2f_lo(q0.x), v1 = wt.x * b2f_hi(q0.x);
  float v2 = wt.x * b2f_lo(q0.y), v3 = wt.x * b2f_hi(q0.y);
  float v4 = wt.x * b2f_lo(q0.z), v5 = wt.x * b2f_hi(q0.z);
  float v6 = wt.x * b2f_lo(q0.w), v7 = wt.x * b2f_hi(q0.w);
  v0 += wt.y * b2f_lo(q1.x); v1 += wt.y * b2f_hi(q1.x);
  v2 += wt.y * b2f_lo(q1.y); v3 += wt.y * b2f_hi(q1.y);
  v4 += wt.y * b2f_lo(q1.z); v5 += wt.y * b2f_hi(q1.z);
  v6 += wt.y * b2f_lo(q1.w); v7 += wt.y * b2f_hi(q1.w);
  v0 += wt.z * b2f_lo(q2.x); v1 += wt.z * b2f_hi(q2.x);
  v2 += wt.z * b2f_lo(q2.y); v3 += wt.z * b2f_hi(q2.y);
  v4 += wt.z * b2f_lo(q2.z); v5 += wt.z * b2f_hi(q2.z);
  v6 += wt.z * b2f_lo(q2.w); v7 += wt.z * b2f_hi(q2.w);
  v0 += wt.w * b2f_lo(q3.x); v1 += wt.w * b2f_hi(q3.x);
  v2 += wt.w * b2f_lo(q3.y); v3 += wt.w * b2f_hi(q3.y);
  v4 += wt.w * b2f_lo(q3.z); v5 += wt.w * b2f_hi(q3.z);
  v6 += wt.w * b2f_lo(q3.w); v7 += wt.w * b2f_hi(q3.w);
  uint4 r;
  r.x = (unsigned)f2b(v0) | ((unsigned)f2b(v1) << 16);
  r.y = (unsigned)f2b(v2) | ((unsigned)f2b(v3) << 16);
  r.z = (unsigned)f2b(v4) | ((unsigned)f2b(v5) << 16);
  r.w = (unsigned)f2b(v6) | ((unsigned)f2b(v7) << 16);
  *(uint4*)dst = r;
}

__global__ __launch_bounds__(256) void dcn_fused(
    const unsigned short* __restrict__ xt, const float* __restrict__ off,
    const float* __restrict__ mask, const __bf16* __restrict__ wbf,
    const float* __restrict__ bias, float* __restrict__ out) {
  extern __shared__ char smem_raw[];
  __bf16* As = (__bf16*)smem_raw;                        // 2 x 16384 el = 65536 B
  __bf16* Bs = As + 32768;                               // 2 x 2048 el  =  8192 B
  float* swt = (float*)(Bs + 4096);                      // [9][32][4] f32 = 4608 B
  unsigned short* sidx = (unsigned short*)(swt + 1152);  // [9][32][4] u16 = 2304 B

  const int bid = blockIdx.x;
  const int id = ((bid & 7) << 6) | (bid >> 3);  // bijective, XCD-contiguous (512=8*64)
  const int b = id >> 7;
  const int nt = (id >> 1) & 63;  // h row
  const int nh = id & 1;          // half: w in [nh*32, nh*32+32)

  const int tid = threadIdx.x;
  const int lane = tid & 63;
  const int wm = tid >> 6;  // 4 waves along m
  const int lh = lane & 15, lg = lane >> 4;

  // ---- precompute per-(pos,k) tap weights & packed indices ----
  for (int e = tid; e < 288; e += 256) {
    const int k = e >> 5;    // 0..8
    const int pl = e & 31;   // 0..31
    const int w = nh * 32 + pl;
    float oy = off[(((size_t)b * 18 + 2 * k) * 64 + nt) * 64 + w];
    float ox = off[(((size_t)b * 18 + 2 * k + 1) * 64 + nt) * 64 + w];
    float m = mask[(((size_t)b * 9 + k) * 64 + nt) * 64 + w];
    float py = oy + (float)(nt - 1 + k / 3);
    float px = ox + (float)(w - 1 + k % 3);
    float y0f = floorf(py), x0f = floorf(px);
    float ly = py - y0f, lx = px - x0f;
    float hy = 1.f - ly, hx = 1.f - lx;
    int y0 = (int)y0f, x0 = (int)x0f;
    int y1 = y0 + 1, x1 = x0 + 1;
    bool vy0 = (y0 >= 0) && (y0 < 64);
    bool vy1 = (y1 >= 0) && (y1 < 64);
    bool vx0 = (x0 >= 0) && (x0 < 64);
    bool vx1 = (x1 >= 0) && (x1 < 64);
    int yc0 = min(max(y0, 0), 63), yc1 = min(max(y1, 0), 63);
    int xc0 = min(max(x0, 0), 63), xc1 = min(max(x1, 0), 63);
    unsigned short* sp = sidx + (k * 32 + pl) * 4;
    float* wp = swt + (k * 32 + pl) * 4;
    sp[0] = (unsigned short)(yc0 * 64 + xc0);
    sp[1] = (unsigned short)(yc0 * 64 + xc1);
    sp[2] = (unsigned short)(yc1 * 64 + xc0);
    sp[3] = (unsigned short)(yc1 * 64 + xc1);
    wp[0] = (vy0 && vx0) ? hy * hx * m : 0.f;
    wp[1] = (vy0 && vx1) ? hy * lx * m : 0.f;
    wp[2] = (vy1 && vx0) ? ly * hx * m : 0.f;
    wp[3] = (vy1 && vx1) ? ly * lx * m : 0.f;
  }

  // ---- A staging geometry: 8 G2L/phase, 32-wide subtile XOR swizzle ----
  const int rowA = tid >> 2;                        // 0..63
  const int swzA = (tid & 3) ^ ((rowA >> 1) & 3);
  const __bf16* aBase = wbf + (size_t)rowA * 2304 + swzA * 8;

  // ---- B build geometry ----
  const int pos = tid >> 3;  // 0..31
  const int ci = tid & 7;
  const unsigned short* xtb = xt + (size_t)b * 1048576 + ci * 8;
  const int bsw = (ci >> 2) * 1024 + pos * 32 + (((ci & 3) ^ ((pos >> 1) & 3)) * 8);

  // ---- MFMA fragment offsets ----
  const int csw = (lg ^ ((lh >> 1) & 3)) * 8;
  int aoff[4], boff[2];
#pragma unroll
  for (int fm = 0; fm < 4; ++fm) aoff[fm] = (wm * 64 + fm * 16 + lh) * 32 + csw;
#pragma unroll
  for (int fn = 0; fn < 2; ++fn) boff[fn] = (fn * 16 + lh) * 32 + csw;

#define MFMA_PHASE(BUF)                                                            \
  do {                                                                             \
    const __bf16* Ab = As + (BUF) * 16384;                                         \
    const __bf16* Bb = Bs + (BUF) * 2048;                                          \
    bf16x8 a0[4], a1[4], b0[2], b1[2];                                             \
    _Pragma("unroll") for (int fm = 0; fm < 4; ++fm) {                             \
      a0[fm] = *(const bf16x8*)(Ab + aoff[fm]);                                    \
      a1[fm] = *(const bf16x8*)(Ab + 8192 + aoff[fm]);                             \
    }                                                                              \
    _Pragma("unroll") for (int fn = 0; fn < 2; ++fn) {                             \
      b0[fn] = *(const bf16x8*)(Bb + boff[fn]);                                    \
      b1[fn] = *(const bf16x8*)(Bb + 1024 + boff[fn]);                             \
    }                                                                              \
    _Pragma("unroll") for (int fm = 0; fm < 4; ++fm)                               \
        _Pragma("unroll") for (int fn = 0; fn < 2; ++fn) {                         \
      acc[fm][fn] = __builtin_amdgcn_mfma_f32_16x16x32_bf16(a0[fm], b0[fn],        \
                                                            acc[fm][fn], 0, 0, 0); \
      acc[fm][fn] = __builtin_amdgcn_mfma_f32_16x16x32_bf16(a1[fm], b1[fn],        \
                                                            acc[fm][fn], 0, 0, 0); \
    }                                                                              \
  } while (0)

#define WAIT_BAR(N)                                                                \
  do {                                                                             \
    asm volatile("s_waitcnt vmcnt(" #N ") lgkmcnt(0)" ::: "memory");               \
    __builtin_amdgcn_sched_barrier(0);                                             \
    __builtin_amdgcn_s_barrier();                                                  \
  } while (0)

#define STAGE_A(KT, BUF)                                                           \
  do {                                                                             \
    __bf16* AsD = As + (BUF) * 16384 + tid * 8;                                    \
    const __bf16* s = aBase + (KT) * 64;                                           \
    G2L(s, AsD);                                                                   \
    G2L(s + 147456, AsD + 2048);                                                   \
    G2L(s + 294912, AsD + 4096);                                                   \
    G2L(s + 442368, AsD + 6144);                                                   \
    G2L(s + 32, AsD + 8192);                                                       \
    G2L(s + 147488, AsD + 10240);                                                  \
    G2L(s + 294944, AsD + 12288);                                                  \
    G2L(s + 442400, AsD + 14336);                                                  \
  } while (0)

#define LOADTAPS(Q0, Q1, Q2, Q3, KIDX, CO)                                         \
  do {                                                                             \
    uint2 su = *(const uint2*)(sidx + (KIDX) * 4);                                 \
    Q0 = *(const uint4*)(xtb + ((su.x & 0xFFFFu) << 8) + (CO));                    \
    Q1 = *(const uint4*)(xtb + ((su.x >> 16) << 8) + (CO));                        \
    Q2 = *(const uint4*)(xtb + ((su.y & 0xFFFFu) << 8) + (CO));                    \
    Q3 = *(const uint4*)(xtb + ((su.y >> 16) << 8) + (CO));                        \
  } while (0)

  // phase p: stage A(tile p+1); taps(tile p+2) -> QL; combine(QC = taps(p+1));
  // MFMA(tile p); counted wait retires the 8 G2L, leaves 4 taps in flight.
#define PHASE(P_, QL0, QL1, QL2, QL3, QC0, QC1, QC2, QC3)                          \
  do {                                                                             \
    const int kt1 = (P_) + 1, kt2 = (P_) + 2;                                      \
    STAGE_A(kt1, kt1 & 1);                                                         \
    __builtin_amdgcn_sched_barrier(0);                                             \
    float4 wt4 = *(const float4*)(swt + ((kt1 >> 2) * 32 + pos) * 4);              \
    LOADTAPS(QL0, QL1, QL2, QL3, (kt2 >> 2) * 32 + pos, (kt2 & 3) * 64);           \
    combine8(QC0, QC1, QC2, QC3, wt4, Bs + (kt1 & 1) * 2048 + bsw);                \
    __builtin_amdgcn_s_setprio(1);                                                 \
    MFMA_PHASE((P_) & 1);                                                          \
    __builtin_amdgcn_s_setprio(0);                                                 \
    WAIT_BAR(4);                                                                   \
  } while (0)

  f32x4 acc[4][2] = {};
  uint4 qA0, qA1, qA2, qA3, qB0, qB1, qB2, qB3;

  __syncthreads();  // swt/sidx ready

  // ---- prologue: tile0 build + tile0 A-stage + tile1 taps ----
  {
    float4 wt0 = *(const float4*)(swt + pos * 4);
    LOADTAPS(qA0, qA1, qA2, qA3, pos, 0);
    combine8(qA0, qA1, qA2, qA3, wt0, Bs + bsw);
    STAGE_A(0, 0);
    __builtin_amdgcn_sched_barrier(0);
    LOADTAPS(qB0, qB1, qB2, qB3, pos, 64);
    WAIT_BAR(4);
  }

  for (int p = 0; p < 34; p += 2) {
    PHASE(p, qA0, qA1, qA2, qA3, qB0, qB1, qB2, qB3);
    PHASE(p + 1, qB0, qB1, qB2, qB3, qA0, qA1, qA2, qA3);
  }
  // ---- tail: phase 34 handled by loop; finish 35 ----
  {
    STAGE_A(35, 1);
    float4 wt4 = *(const float4*)(swt + (8 * 32 + pos) * 4);
    combine8(qB0, qB1, qB2, qB3, wt4, Bs + 2048 + bsw);
    __builtin_amdgcn_s_setprio(1);
    MFMA_PHASE(0);
    __builtin_amdgcn_s_setprio(0);
    WAIT_BAR(0);
    MFMA_PHASE(1);
  }

  // ---- epilogue ----
  float* outb = out + (size_t)b * 1048576 + (size_t)(nt * 64 + nh * 32);
#pragma unroll
  for (int fm = 0; fm < 4; ++fm) {
#pragma unroll
    for (int i = 0; i < 4; ++i) {
      const int o = wm * 64 + fm * 16 + lg * 4 + i;
      const float bs = bias[o];
      float* orow = outb + (size_t)o * 4096 + lh;
#pragma unroll
      for (int fn = 0; fn < 2; ++fn) orow[fn * 16] = acc[fm][fn][i] + bs;
    }
  }
#undef MFMA_PHASE
#undef WAIT_BAR
#undef STAGE_A
#undef LOADTAPS
#undef PHASE
}

extern "C" void kernel_launch(void* const* d_in, const int* in_sizes, int n_in,
                              void* d_out, int out_size, void* d_ws, size_t ws_size,
                              hipStream_t stream) {
  const float* x = (const float*)d_in[0];
  const float* off = (const float*)d_in[1];
  const float* mask = (const float*)d_in[2];
  const float* wgt = (const float*)d_in[3];
  const float* bias = (const float*)d_in[4];
  float* out = (float*)d_out;

  unsigned short* wbf = (unsigned short*)d_ws;   // 256*2304 bf16 = 1.2 MB
  unsigned short* xtp = wbf + 589824ull;         // 4*64*64*256 bf16 = 8.4 MB

  const int smem_bytes = 65536 + 8192 + 4608 + 2304;  // 80640 -> 2 blocks/CU
  (void)hipFuncSetAttribute(reinterpret_cast<const void*>(&dcn_fused),
                            hipFuncAttributeMaxDynamicSharedMemorySize, smem_bytes);

  cast_weight<<<2304, 256, 0, stream>>>(wgt, wbf);
  transpose_x<<<1024, 256, 0, stream>>>(x, xtp);
  dcn_fused<<<512, 256, smem_bytes, stream>>>(xtp, off, mask, (const __bf16*)wbf,
                                              bias, out);
}